// Round 7
// baseline (257.483 us; speedup 1.0000x reference)
//
#include <hip/hip_runtime.h>
#include <hip/hip_bf16.h>

#define KE_F   332.0636f
#define MAX_M  1024   // padded molecule count (harness M = 1000)
#define BLK    256
#define NBLK   2048
#define WCHUNK 256    // edges per wave-chunk (4 per lane)

typedef int   ivec2 __attribute__((ext_vector_type(2)));
typedef float fvec4 __attribute__((ext_vector_type(4)));

__device__ __forceinline__ float softplusf(float x) {
    return logf(1.0f + expf(x));
}

// Zero-instruction scheduling fence (R6-proven): pins LDS/VMEM ops.
__device__ __forceinline__ void wave_fence() {
    __builtin_amdgcn_wave_barrier();
    asm volatile("" ::: "memory");
}

// asm VMEM: vdst, 32-bit VGPR voffset, 64-bit SGPR base. All loop VMEM goes
// through these so OUR counted s_waitcnt is the only vmcnt authority
// (mixing compiler loads with counted waits over/under-drains — see R6 PM).
#define GLOAD2(dst, base, voff)                                     \
    asm volatile("global_load_dwordx2 %0, %1, %2"                   \
                 : "=v"(dst) : "v"(voff), "s"(base) : "memory")
#define GLOAD4(dst, base, voff)                                     \
    asm volatile("global_load_dwordx4 %0, %1, %2"                   \
                 : "=v"(dst) : "v"(voff), "s"(base) : "memory")
// Counted wait + sched_barrier(0) (rule #18: math must not hoist past it).
#define WAITV(n) do {                                               \
    asm volatile("s_waitcnt vmcnt(" #n ")" ::: "memory");           \
    __builtin_amdgcn_sched_barrier(0); } while (0)

// One block: prefix-scan num_atoms -> mol_starts[M+1]; derived constants into
// params: [0..3]=c_k/sum(c), [4..7]=exponents_k/d, [16..111]=Z^zexp table;
// also zeroes out[0..M) (harness re-poisons d_out each launch).
__global__ void scan_params_kernel(const int* __restrict__ num_atoms, int M,
                                   const float* __restrict__ d_inv,
                                   const float* __restrict__ z_exp_inv,
                                   const float* __restrict__ c_inv,
                                   const float* __restrict__ exp_inv,
                                   int* __restrict__ mol_starts,
                                   float* __restrict__ params,
                                   float* __restrict__ out) {
    __shared__ int buf[MAX_M];
    int t = threadIdx.x;
    buf[t] = (t < M) ? num_atoms[t] : 0;
    __syncthreads();
    for (int off = 1; off < MAX_M; off <<= 1) {
        int x = (t >= off) ? buf[t - off] : 0;
        __syncthreads();
        buf[t] += x;
        __syncthreads();
    }
    if (t == 0) mol_starts[0] = 0;
    if (t < M) mol_starts[t + 1] = buf[t];
    if (t == 0) {
        float dd = softplusf(d_inv[0]);
        float c0 = softplusf(c_inv[0]), c1 = softplusf(c_inv[1]);
        float c2 = softplusf(c_inv[2]), c3 = softplusf(c_inv[3]);
        float e0 = softplusf(exp_inv[0]), e1 = softplusf(exp_inv[1]);
        float e2 = softplusf(exp_inv[2]), e3 = softplusf(exp_inv[3]);
        float ic = 1.0f / (c0 + c1 + c2 + c3);
        float id = 1.0f / dd;
        params[0] = c0 * ic; params[1] = c1 * ic; params[2] = c2 * ic; params[3] = c3 * ic;
        params[4] = e0 * id; params[5] = e1 * id; params[6] = e2 * id; params[7] = e3 * id;
    }
    if (t < 96) {
        float zexp = softplusf(z_exp_inv[0]);
        params[16 + t] = __powf((float)t, zexp);
    }
    for (int k = t; k < M; k += MAX_M) out[k] = 0.0f;
}

// pack[a] = (x, y, z, float((mol<<7)|Z)); mol via binary search (clamps,
// matching jnp.repeat total_repeat_length pad).
__global__ void pack_kernel(const float* __restrict__ xyz,
                            const int* __restrict__ z,
                            const int* __restrict__ mol_starts, int M, int N,
                            float4* __restrict__ pack) {
    int a = blockIdx.x * blockDim.x + threadIdx.x;
    if (a >= N) return;
    int lo = 0, hi = M;
    while (hi - lo > 1) {
        int mid = (lo + hi) >> 1;
        if (mol_starts[mid] <= a) lo = mid; else hi = mid;
    }
    pack[a] = make_float4(xyz[3 * a + 0], xyz[3 * a + 1], xyz[3 * a + 2],
                          (float)((lo << 7) | z[a]));
}

// Asm-enforced software pipeline over R6's coalesced SoA layout.
// Evidence: R6 VGPR=36 proves the compiler serializes the gather batch and
// drains per chunk (stream-wait -> gather-wait -> math). Here all loop VMEM
// is inline asm with counted waits; steady-state in-flight invariant:
//   stream[c+1] (7 loads, OLDER) + gathers[c] (8 loads, NEWER)
// vmcnt(8) retires exactly the stream, vmcnt(7) exactly the gathers (FIFO
// retire). Stream latency hides under math[c-1]; gather latency under
// math[c]+next front-half. Line counts identical to R6 (clean variable).
__global__ __launch_bounds__(BLK) void nr_main_kernel(
    const int* __restrict__ nbrs, const float* __restrict__ offsets,
    const float4* __restrict__ pack,
    const float* __restrict__ params, float* __restrict__ out, int E, int M) {
    __shared__ float sm[MAX_M];
    __shared__ float zp[96];
    __shared__ float sof[4][WCHUNK * 3];   // 12 KB: per-wave offset bounce
    for (int t = threadIdx.x; t < MAX_M; t += BLK) sm[t] = 0.0f;
    if (threadIdx.x < 96) zp[threadIdx.x] = params[16 + threadIdx.x];
    __syncthreads();

    const float4 kk = *(const float4*)(params + 0);
    const float4 gg = *(const float4*)(params + 4);

    const int lane = threadIdx.x & 63;
    float* myof = sof[threadIdx.x >> 6];

    const int nchunks = E / WCHUNK;
    const int gw = (blockIdx.x * BLK + threadIdx.x) >> 6;   // global wave id
    const int nw = (gridDim.x * BLK) >> 6;

// stream for chunk ch: 4 coalesced dwordx2 (nbrs) + 3 coalesced dwordx4
// (offsets) = exactly 7 VMEM ops (the "7" in the vmcnt counting).
#define ISSUE_S(ch) do {                                                      \
        const uint32_t _nbo = (uint32_t)(ch) * (WCHUNK * 8u)  + (uint32_t)lane * 8u;  \
        GLOAD2(nb0, nbrs, _nbo);                                              \
        GLOAD2(nb1, nbrs, _nbo + 512u);                                       \
        GLOAD2(nb2, nbrs, _nbo + 1024u);                                      \
        GLOAD2(nb3, nbrs, _nbo + 1536u);                                      \
        const uint32_t _ofo = (uint32_t)(ch) * (WCHUNK * 12u) + (uint32_t)lane * 16u; \
        GLOAD4(F0, offsets, _ofo);                                            \
        GLOAD4(F1, offsets, _ofo + 1024u);                                    \
        GLOAD4(F2, offsets, _ofo + 2048u);                                    \
    } while (0)

// masks + byte-voffsets from nb regs (masked lanes -> record 0, 1 bcast line)
#define MKADDR(mm, vv) do {                                                   \
        mm[0] = nb0.y > nb0.x; mm[1] = nb1.y > nb1.x;                         \
        mm[2] = nb2.y > nb2.x; mm[3] = nb3.y > nb3.x;                         \
        vv[0] = (uint32_t)(mm[0] ? nb0.x : 0) * 16u;                          \
        vv[1] = (uint32_t)(mm[0] ? nb0.y : 0) * 16u;                          \
        vv[2] = (uint32_t)(mm[1] ? nb1.x : 0) * 16u;                          \
        vv[3] = (uint32_t)(mm[1] ? nb1.y : 0) * 16u;                          \
        vv[4] = (uint32_t)(mm[2] ? nb2.x : 0) * 16u;                          \
        vv[5] = (uint32_t)(mm[2] ? nb2.y : 0) * 16u;                          \
        vv[6] = (uint32_t)(mm[3] ? nb3.x : 0) * 16u;                          \
        vv[7] = (uint32_t)(mm[3] ? nb3.y : 0) * 16u;                          \
    } while (0)

// exactly 8 VMEM ops (the "8" in the vmcnt counting)
#define ISSUE_G(vv) do {                                                      \
        GLOAD4(gi0, pack, vv[0]); GLOAD4(gj0, pack, vv[1]);                   \
        GLOAD4(gi1, pack, vv[2]); GLOAD4(gj1, pack, vv[3]);                   \
        GLOAD4(gi2, pack, vv[4]); GLOAD4(gj2, pack, vv[5]);                   \
        GLOAD4(gi3, pack, vv[6]); GLOAD4(gj3, pack, vv[7]);                   \
    } while (0)

#define DSWRITE_F() do {                                                      \
        *(fvec4*)&myof[4 * lane]       = F0;                                  \
        *(fvec4*)&myof[4 * lane + 256] = F1;                                  \
        *(fvec4*)&myof[4 * lane + 512] = F2;                                  \
    } while (0)

// per-edge math — bitwise-identical to the verified R0/R6 arithmetic
#define EDGE(h, GI, GJ) do {                                                  \
        const float dx = GI.x - GJ.x - o[3 * h + 0];                          \
        const float dy = GI.y - GJ.y - o[3 * h + 1];                          \
        const float dz = GI.z - GJ.z - o[3 * h + 2];                          \
        const float r2 = fmaf(dx, dx, fmaf(dy, dy, dz * dz)) + 3e-15f;        \
        const bool ok = m[h] && (r2 < 25.0f);                                 \
        const int  wi = (int)GI.w;                                            \
        const int  wj = (int)GJ.w;                                            \
        const float zi = (float)(wi & 127);                                   \
        const float zj = (float)(wj & 127);                                   \
        const float inv_r = rsqrtf(r2);                                       \
        const float r = r2 * inv_r;                                           \
        const float S = zp[wi & 127] + zp[wj & 127];                          \
        const float rs = r * S;                                               \
        const float phi = kk.x * __expf(-gg.x * rs) + kk.y * __expf(-gg.y * rs) + \
                          kk.z * __expf(-gg.z * rs) + kk.w * __expf(-gg.w * rs);  \
        const float fc = __expf(-__fdividef(r2, 25.0f - r2));                 \
        const float val = KE_F * zi * zj * inv_r * phi * fc;                  \
        if (ok) atomicAdd(&sm[wi >> 7], val);                                 \
    } while (0)

    int c = gw;
    if (c < nchunks) {
        ivec2 nb0, nb1, nb2, nb3;          // stream regs (asm-pinned)
        fvec4 F0, F1, F2;
        fvec4 gi0, gj0, gi1, gj1, gi2, gj2, gi3, gj3;   // gather regs (asm-pinned)
        bool  m[4];

        // --- prologue: one full drain, then establish the invariant ---
        ISSUE_S(c);
        WAITV(0);
        wave_fence();
        DSWRITE_F();                       // LDS = off[c]
        wave_fence();
        uint32_t vo[8];
        MKADDR(m, vo);
        int nx = c + nw; if (nx >= nchunks) nx = nchunks - 1;   // clamp: dup-load, never dup-processed
        ISSUE_S(nx);                       // in flight: s[nx](7)
        ISSUE_G(vo);                       // in flight: s[nx](7 old) + G[c](8 new)

        for (;;) {
            WAITV(8);                      // retire exactly s[nx]; G[c] keeps flying
            wave_fence();
            float o[12];                   // copy off[c] out before overwrite (WAR)
#pragma unroll
            for (int h = 0; h < 4; ++h) {
                o[3 * h + 0] = myof[192 * h + 3 * lane + 0];
                o[3 * h + 1] = myof[192 * h + 3 * lane + 1];
                o[3 * h + 2] = myof[192 * h + 3 * lane + 2];
            }
            wave_fence();
            DSWRITE_F();                   // LDS = off[nx]
            wave_fence();
            bool mn[4]; uint32_t von[8];
            MKADDR(mn, von);               // nb regs consumed; free for reissue
            int nx2 = c + 2 * nw; if (nx2 >= nchunks) nx2 = nchunks - 1;
            ISSUE_S(nx2);                  // in flight: G[c](8 old) + s[nx2](7 new)
            WAITV(7);                      // retire exactly G[c] -> g regs valid
            EDGE(0, gi0, gj0);             // s[nx2] latency hides under math
            EDGE(1, gi1, gj1);
            EDGE(2, gi2, gj2);
            EDGE(3, gi3, gj3);
            ISSUE_G(von);                  // in flight: s[nx2](7 old) + G[nx](8 new)
            m[0] = mn[0]; m[1] = mn[1]; m[2] = mn[2]; m[3] = mn[3];
            c += nw;
            if (c >= nchunks) break;       // wave-uniform
        }
        WAITV(0);                          // drain dangling clamped loads before
                                           // any compiler VMEM (reg reuse hazard)
    }

#undef ISSUE_S
#undef MKADDR
#undef ISSUE_G
#undef DSWRITE_F
#undef EDGE

    // Tail edges [nchunks*WCHUNK, E) — scalar path (empty in harness).
    const int stride = gridDim.x * BLK;
    for (int e = nchunks * WCHUNK + blockIdx.x * BLK + threadIdx.x; e < E; e += stride) {
        const int i = nbrs[2 * e], j = nbrs[2 * e + 1];
        if (j <= i) continue;
        const float oxs = offsets[3 * e], oys = offsets[3 * e + 1], ozs = offsets[3 * e + 2];
        const float4 pis = pack[i], pjs = pack[j];
        const float dx = pis.x - pjs.x - oxs;
        const float dy = pis.y - pjs.y - oys;
        const float dz = pis.z - pjs.z - ozs;
        const float r2 = fmaf(dx, dx, fmaf(dy, dy, dz * dz)) + 3e-15f;
        if (r2 >= 25.0f) continue;
        const int  wi = (int)pis.w;
        const int  wj = (int)pjs.w;
        const float inv_r = rsqrtf(r2);
        const float r = r2 * inv_r;
        const float S = zp[wi & 127] + zp[wj & 127];
        const float rs = r * S;
        const float phi = kk.x * __expf(-gg.x * rs) + kk.y * __expf(-gg.y * rs) +
                          kk.z * __expf(-gg.z * rs) + kk.w * __expf(-gg.w * rs);
        const float fc = __expf(-__fdividef(r2, 25.0f - r2));
        atomicAdd(&sm[wi >> 7],
                  KE_F * (float)(wi & 127) * (float)(wj & 127) * inv_r * phi * fc);
    }

    __syncthreads();
    // Sparse flush: ~35% of slots nonzero per block -> ~0.7M global atomics.
    for (int t = threadIdx.x; t < M; t += BLK) {
        const float v = sm[t];
        if (v != 0.0f) atomicAdd(&out[t], v);
    }
}

extern "C" void kernel_launch(void* const* d_in, const int* in_sizes, int n_in,
                              void* d_out, int out_size, void* d_ws, size_t ws_size,
                              hipStream_t stream) {
    const float* xyz       = (const float*)d_in[0];
    const int*   z         = (const int*)d_in[1];
    const int*   nbrs      = (const int*)d_in[2];
    const int*   num_atoms = (const int*)d_in[3];
    const float* offsets   = (const float*)d_in[4];
    const float* d_inv     = (const float*)d_in[5];
    const float* z_exp_inv = (const float*)d_in[6];
    const float* c_inv     = (const float*)d_in[7];
    const float* exp_inv   = (const float*)d_in[8];
    float* out = (float*)d_out;

    const int N = in_sizes[0] / 3;
    const int E = in_sizes[2] / 2;
    const int M = in_sizes[3];

    // Workspace: [0,4096) mol_starts; [4096,8192) params; [8192,+16N) pack.
    char* w = (char*)d_ws;
    int*    mol_starts = (int*)w;
    float*  params     = (float*)(w + 4096);
    float4* pack       = (float4*)(w + 8192);

    scan_params_kernel<<<1, MAX_M, 0, stream>>>(num_atoms, M, d_inv, z_exp_inv,
                                                c_inv, exp_inv, mol_starts,
                                                params, out);
    pack_kernel<<<(N + BLK - 1) / BLK, BLK, 0, stream>>>(xyz, z, mol_starts, M, N,
                                                         pack);
    nr_main_kernel<<<NBLK, BLK, 0, stream>>>(nbrs, offsets, pack,
                                             params, out, E, M);
}

// Round 8
// 240.993 us; speedup vs baseline: 1.0684x; 1.0684x over previous
//
#include <hip/hip_runtime.h>
#include <hip/hip_bf16.h>

#define KE_F   332.0636f
#define MAX_M  1024   // padded molecule count (harness M = 1000)
#define BLK    256
#define NBLK   2048   // best measured grid (R0: 84.2 us)
#define WCHUNK 256    // edges per wave-iteration (4 per lane)

typedef int   ivec2 __attribute__((ext_vector_type(2)));
typedef int   ivec4 __attribute__((ext_vector_type(4)));
typedef float fvec4 __attribute__((ext_vector_type(4)));

__device__ __forceinline__ float softplusf(float x) {
    return logf(1.0f + expf(x));
}

// Compile-time fence: no instruction emitted; blocks the scheduler from
// moving LDS/VMEM ops across it (wave-synchronous LDS exchange idiom).
__device__ __forceinline__ void wave_fence() {
    __builtin_amdgcn_wave_barrier();
    asm volatile("" ::: "memory");
}

// One block: prefix-scan num_atoms -> mol_starts[M+1]; derived constants into
// params: [0..3]=c_k/sum(c), [4..7]=exponents_k/d, [16..111]=Z^zexp table;
// also zeroes out[0..M) (harness re-poisons d_out to 0xAA each launch).
__global__ void scan_params_kernel(const int* __restrict__ num_atoms, int M,
                                   const float* __restrict__ d_inv,
                                   const float* __restrict__ z_exp_inv,
                                   const float* __restrict__ c_inv,
                                   const float* __restrict__ exp_inv,
                                   int* __restrict__ mol_starts,
                                   float* __restrict__ params,
                                   float* __restrict__ out) {
    __shared__ int buf[MAX_M];
    int t = threadIdx.x;
    buf[t] = (t < M) ? num_atoms[t] : 0;
    __syncthreads();
    for (int off = 1; off < MAX_M; off <<= 1) {   // Hillis-Steele inclusive scan
        int x = (t >= off) ? buf[t - off] : 0;
        __syncthreads();
        buf[t] += x;
        __syncthreads();
    }
    if (t == 0) mol_starts[0] = 0;
    if (t < M) mol_starts[t + 1] = buf[t];
    if (t == 0) {
        float dd = softplusf(d_inv[0]);
        float c0 = softplusf(c_inv[0]), c1 = softplusf(c_inv[1]);
        float c2 = softplusf(c_inv[2]), c3 = softplusf(c_inv[3]);
        float e0 = softplusf(exp_inv[0]), e1 = softplusf(exp_inv[1]);
        float e2 = softplusf(exp_inv[2]), e3 = softplusf(exp_inv[3]);
        float ic = 1.0f / (c0 + c1 + c2 + c3);
        float id = 1.0f / dd;
        params[0] = c0 * ic; params[1] = c1 * ic; params[2] = c2 * ic; params[3] = c3 * ic;
        params[4] = e0 * id; params[5] = e1 * id; params[6] = e2 * id; params[7] = e3 * id;
    }
    if (t < 96) {                                  // z in [1,94): table of Z^zexp
        float zexp = softplusf(z_exp_inv[0]);
        params[16 + t] = __powf((float)t, zexp);
    }
    for (int k = t; k < M; k += MAX_M) out[k] = 0.0f;
}

// Per-atom packing: pack[a] = (x, y, z, encode(mol, Z)) where
// encode = float((mol << 7) | Z)  (exact: < 2^17). mol via binary search on
// mol_starts (clamps to M-1, matching jnp.repeat total_repeat_length pad).
__global__ void pack_kernel(const float* __restrict__ xyz,
                            const int* __restrict__ z,
                            const int* __restrict__ mol_starts, int M, int N,
                            float4* __restrict__ pack) {
    int a = blockIdx.x * blockDim.x + threadIdx.x;
    if (a >= N) return;
    int lo = 0, hi = M;
    while (hi - lo > 1) {
        int mid = (lo + hi) >> 1;
        if (mol_starts[mid] <= a) lo = mid; else hi = mid;
    }
    pack[a] = make_float4(xyz[3 * a + 0], xyz[3 * a + 1], xyz[3 * a + 2],
                          (float)((lo << 7) | z[a]));
}

// Wave-cooperative SoA edge consumption, barrier-free (R6, the session's
// verified best: nr_main 74.5us, absmax 0.0). Kept verbatim after R7's
// asm-pipeline attempt regressed (105us, FETCH +36% from lost nt hints,
// absmax 75776 from vmcnt-count hazard vs compiler-emitted VMEM).
//
// Two-floor / line-transaction model (R0-R7 evidence):
//  - consecutive LANES take consecutive edges: nbrs as per-lane int2 ->
//    8 lines per 64 edges (R0 AoS: 16); offsets via 3 coalesced fvec4
//    per 256 edges bounced through WAVE-PRIVATE LDS -> 12 lines per 64
//    edges (R0: ~36). Stream lookups 52 -> 20 per 64 edges.
//  - gathers + math bitwise-identical to R0 (absmax 0.0); all 8 gathers
//    of a lane's 4 edges issued back-to-back BEFORE the LDS-write section
//    so gather issue never waits on the offset-load vmcnt.
//  - wave_fence() pins the LDS bounce ordering (R5 failure: without it
//    the scheduler hoists the ds_reads past the ds_writes).
__global__ __launch_bounds__(BLK) void nr_main_kernel(
    const int* __restrict__ nbrs, const float* __restrict__ offsets,
    const float4* __restrict__ pack,
    const float* __restrict__ params, float* __restrict__ out, int E, int M) {
    __shared__ float sm[MAX_M];
    __shared__ float zp[96];
    __shared__ float sof[4][WCHUNK * 3];   // 12 KB: per-wave offset bounce
    for (int t = threadIdx.x; t < MAX_M; t += BLK) sm[t] = 0.0f;
    if (threadIdx.x < 96) zp[threadIdx.x] = params[16 + threadIdx.x];
    __syncthreads();

    const float4 kk = *(const float4*)(params + 0);   // phi coefficients
    const float4 gg = *(const float4*)(params + 4);   // exponent scales (/d folded)

    const int lane = threadIdx.x & 63;
    float* myof = sof[threadIdx.x >> 6];              // this wave's private region

    const int nchunks = E / WCHUNK;
    const int gw = (blockIdx.x * BLK + threadIdx.x) >> 6;   // global wave id
    const int nw = (gridDim.x * BLK) >> 6;                  // total waves

    const ivec2* nbp = (const ivec2*)nbrs;
    const fvec4* of4 = (const fvec4*)offsets;

    for (int c = gw; c < nchunks; c += nw) {
        const size_t eb = (size_t)c * WCHUNK;
        // nbrs: per-lane int2, perfectly coalesced (512B/instr).
        ivec2 nb[4];
#pragma unroll
        for (int h = 0; h < 4; ++h)
            nb[h] = __builtin_nontemporal_load(nbp + eb + 64 * h + lane);
        // offsets: 3 coalesced float4 instrs (1024B each), for LDS bounce.
        const fvec4* ofb = of4 + (size_t)c * ((WCHUNK * 3) / 4);
        const fvec4 F0 = __builtin_nontemporal_load(ofb + lane);
        const fvec4 F1 = __builtin_nontemporal_load(ofb + 64 + lane);
        const fvec4 F2 = __builtin_nontemporal_load(ofb + 128 + lane);

        // Issue ALL 8 gathers batched, branch-free (masked lanes -> line 0),
        // before the LDS-write section (no vmcnt dependence on F0-F2).
        bool   m[4];
        float4 pi[4], pj[4];
#pragma unroll
        for (int h = 0; h < 4; ++h) {
            const int iv = nb[h].x, jv = nb[h].y;
            m[h] = jv > iv;
            pi[h] = pack[m[h] ? iv : 0];
            pj[h] = pack[m[h] ? jv : 0];
        }

        wave_fence();   // WAR: prev iteration's LDS reads complete first
        *(fvec4*)&myof[4 * lane]       = F0;   // conflict-free b128 writes;
        *(fvec4*)&myof[4 * lane + 256] = F1;   // myof[f] = offsets[768c+f]
        *(fvec4*)&myof[4 * lane + 512] = F2;
        wave_fence();   // RAW: reads below must not hoist above the writes

#pragma unroll
        for (int h = 0; h < 4; ++h) {
            // lane's edge h = eb + 64h + lane; its floats at 192h+3*lane.
            const float oxv = myof[192 * h + 3 * lane + 0];
            const float oyv = myof[192 * h + 3 * lane + 1];
            const float ozv = myof[192 * h + 3 * lane + 2];
            const float dx = pi[h].x - pj[h].x - oxv;
            const float dy = pi[h].y - pj[h].y - oyv;
            const float dz = pi[h].z - pj[h].z - ozv;
            const float r2 = fmaf(dx, dx, fmaf(dy, dy, dz * dz)) + 3e-15f;
            const bool ok = m[h] && (r2 < 25.0f);
            const int  wi = (int)pi[h].w;
            const int  wj = (int)pj[h].w;
            const float zi = (float)(wi & 127);
            const float zj = (float)(wj & 127);
            const float inv_r = rsqrtf(r2);
            const float r = r2 * inv_r;
            const float S = zp[wi & 127] + zp[wj & 127];
            const float rs = r * S;
            const float phi = kk.x * __expf(-gg.x * rs) + kk.y * __expf(-gg.y * rs) +
                              kk.z * __expf(-gg.z * rs) + kk.w * __expf(-gg.w * rs);
            const float fc = __expf(-__fdividef(r2, 25.0f - r2));
            const float val = KE_F * zi * zj * inv_r * phi * fc;
            if (ok) atomicAdd(&sm[wi >> 7], val);   // inf/nan of masked lanes discarded
        }
    }

    // Tail edges [nchunks*WCHUNK, E) — scalar path (empty in harness).
    const int stride = gridDim.x * BLK;
    for (int e = nchunks * WCHUNK + blockIdx.x * BLK + threadIdx.x; e < E; e += stride) {
        const int i = nbrs[2 * e], j = nbrs[2 * e + 1];
        if (j <= i) continue;
        const float oxs = offsets[3 * e], oys = offsets[3 * e + 1], ozs = offsets[3 * e + 2];
        const float4 pis = pack[i], pjs = pack[j];
        const float dx = pis.x - pjs.x - oxs;
        const float dy = pis.y - pjs.y - oys;
        const float dz = pis.z - pjs.z - ozs;
        const float r2 = fmaf(dx, dx, fmaf(dy, dy, dz * dz)) + 3e-15f;
        if (r2 >= 25.0f) continue;
        const int  wi = (int)pis.w;
        const int  wj = (int)pjs.w;
        const float inv_r = rsqrtf(r2);
        const float r = r2 * inv_r;
        const float S = zp[wi & 127] + zp[wj & 127];
        const float rs = r * S;
        const float phi = kk.x * __expf(-gg.x * rs) + kk.y * __expf(-gg.y * rs) +
                          kk.z * __expf(-gg.z * rs) + kk.w * __expf(-gg.w * rs);
        const float fc = __expf(-__fdividef(r2, 25.0f - r2));
        atomicAdd(&sm[wi >> 7],
                  KE_F * (float)(wi & 127) * (float)(wj & 127) * inv_r * phi * fc);
    }

    __syncthreads();
    // Sparse flush: ~35% of slots nonzero per block -> ~0.7M global atomics total.
    for (int t = threadIdx.x; t < M; t += BLK) {
        const float v = sm[t];
        if (v != 0.0f) atomicAdd(&out[t], v);
    }
}

extern "C" void kernel_launch(void* const* d_in, const int* in_sizes, int n_in,
                              void* d_out, int out_size, void* d_ws, size_t ws_size,
                              hipStream_t stream) {
    const float* xyz       = (const float*)d_in[0];
    const int*   z         = (const int*)d_in[1];
    const int*   nbrs      = (const int*)d_in[2];
    const int*   num_atoms = (const int*)d_in[3];
    const float* offsets   = (const float*)d_in[4];
    const float* d_inv     = (const float*)d_in[5];
    const float* z_exp_inv = (const float*)d_in[6];
    const float* c_inv     = (const float*)d_in[7];
    const float* exp_inv   = (const float*)d_in[8];
    float* out = (float*)d_out;

    const int N = in_sizes[0] / 3;
    const int E = in_sizes[2] / 2;
    const int M = in_sizes[3];

    // Workspace layout (16B-aligned regions):
    //   [0, 4096)            : mol_starts (M+1 ints)
    //   [4096, 8192)         : params (112 floats used)
    //   [8192, 8192+16N)     : pack (N float4; w = (mol<<7)|Z encoded)
    char* w = (char*)d_ws;
    int*    mol_starts = (int*)w;
    float*  params     = (float*)(w + 4096);
    float4* pack       = (float4*)(w + 8192);

    scan_params_kernel<<<1, MAX_M, 0, stream>>>(num_atoms, M, d_inv, z_exp_inv,
                                                c_inv, exp_inv, mol_starts,
                                                params, out);
    pack_kernel<<<(N + BLK - 1) / BLK, BLK, 0, stream>>>(xyz, z, mol_starts, M, N,
                                                         pack);
    nr_main_kernel<<<NBLK, BLK, 0, stream>>>(nbrs, offsets, pack,
                                             params, out, E, M);
}